// Round 1
// baseline (9954.498 us; speedup 1.0000x reference)
//
#include <hip/hip_runtime.h>
#include <stdint.h>
#include <stddef.h>

#define B_ 16
#define T_ 4096
#define D_ 256
#define H_ 512
#define G3_ 1536

// ws layout
#define OFF_IG   ((size_t)0)                       // igates f16: 65536*1536*2 = 201326592
#define OFF_WT   ((size_t)201326592)               // W_ih^T packed float4: 256*1536*4 = 1572864
#define OFF_HBUF ((size_t)202899456)               // tagged h words: 2*16*512*4 = 65536
#define WS_NEED  ((size_t)202964992)

typedef _Float16 h2_t __attribute__((ext_vector_type(2)));

#if defined(__has_builtin)
#if __has_builtin(__builtin_amdgcn_fdot2)
#define HAVE_FDOT2 1
#endif
#endif

__device__ __forceinline__ float fdot2f(uint32_t w, uint32_t h, float acc) {
  union { uint32_t u; h2_t v; } a, b;
  a.u = w; b.u = h;
#ifdef HAVE_FDOT2
  return __builtin_amdgcn_fdot2(a.v, b.v, acc, false);
#else
  return fmaf((float)a.v.x, (float)b.v.x, fmaf((float)a.v.y, (float)b.v.y, acc));
#endif
}

__device__ __forceinline__ uint32_t packh2(float a, float b) {
  union { h2_t v; uint32_t u; } x;
  x.v.x = (_Float16)a; x.v.y = (_Float16)b;
  return x.u;
}

__device__ __forceinline__ uint32_t f16bits(float a) {
  union { _Float16 h; uint16_t u; } x;
  x.h = (_Float16)a;
  return (uint32_t)x.u;
}

__device__ __forceinline__ float sigmoidf_(float x) {
  return 1.0f / (1.0f + __expf(-x));
}

__device__ __forceinline__ float tanhf_(float x) {
  x = fminf(fmaxf(x, -15.0f), 15.0f);
  float e = __expf(-2.0f * x);
  return (1.0f - e) / (1.0f + e);
}

// ---------------- Kernel 1: transpose+pack W_ih into [d/4][g] float4 ----------------
__global__ void __launch_bounds__(256) wt_kernel(const float* __restrict__ W, float4* __restrict__ Wt4) {
  int idx = blockIdx.x * 256 + threadIdx.x;   // over 1536*64
  if (idx >= G3_ * 64) return;
  int g = idx % G3_;
  int d4 = idx / G3_;
  float4 v = *(const float4*)(W + (size_t)g * D_ + 4 * d4);
  Wt4[(size_t)d4 * G3_ + g] = v;
}

// ---------------- Kernel 2: igates = xs @ W_ih^T + b  -> f16 ----------------
__global__ void __launch_bounds__(256) ig_kernel(const float* __restrict__ xs,
                                                 const float* __restrict__ Wt,
                                                 const float* __restrict__ bias,
                                                 _Float16* __restrict__ ig) {
  __shared__ float xls[16 * 256];
  const int m0 = blockIdx.x * 16;
  const int tid = threadIdx.x;

  // load xs tile (16 rows x 256) cooperatively, coalesced float4
  const float4* xsrc = (const float4*)(xs + (size_t)m0 * D_);
  float4* xdst = (float4*)xls;
#pragma unroll
  for (int k = 0; k < 4; ++k) xdst[tid + 256 * k] = xsrc[tid + 256 * k];
  __syncthreads();

  float acc[6][16];
#pragma unroll
  for (int k = 0; k < 6; ++k)
#pragma unroll
    for (int m = 0; m < 16; ++m) acc[k][m] = 0.0f;

  const float4* Wt4 = (const float4*)Wt;
  const float4* lds4 = (const float4*)xls;

  for (int d4 = 0; d4 < 64; ++d4) {
    float4 w[6];
#pragma unroll
    for (int k = 0; k < 6; ++k) w[k] = Wt4[(size_t)d4 * G3_ + tid + 256 * k];
#pragma unroll
    for (int m = 0; m < 16; ++m) {
      float4 xv = lds4[m * 64 + d4];
#pragma unroll
      for (int k = 0; k < 6; ++k) {
        acc[k][m] = fmaf(w[k].x, xv.x, acc[k][m]);
        acc[k][m] = fmaf(w[k].y, xv.y, acc[k][m]);
        acc[k][m] = fmaf(w[k].z, xv.z, acc[k][m]);
        acc[k][m] = fmaf(w[k].w, xv.w, acc[k][m]);
      }
    }
  }

#pragma unroll
  for (int k = 0; k < 6; ++k) {
    float bb = bias[tid + 256 * k];
#pragma unroll
    for (int m = 0; m < 16; ++m) {
      ig[(size_t)(m0 + m) * G3_ + tid + 256 * k] = (_Float16)(acc[k][m] + bb);
    }
  }
}

// ---------------- Kernel 3: persistent recurrence ----------------
// 128 WGs x 256 threads. WG wg: batch b = wg>>3, col slice sub = wg&7 (64 h-cols).
// Thread: q = tid&3 (K-quarter), cl = tid>>2 (local col), j = sub*64+cl.
// Holds W_hh rows {j, j+512, j+1024} x K[q*128, q*128+128) as 192 packed-f16 VGPRs.
// h exchange: global tagged words (tag<<16)|f16(h), double-buffered, relaxed agent atomics.
__global__ void __launch_bounds__(256, 1) rec_kernel(const _Float16* __restrict__ ig,
                                                     const float* __restrict__ Whh,
                                                     const float* __restrict__ bn,
                                                     uint32_t* __restrict__ hbuf,
                                                     float* __restrict__ out) {
  const int wg = blockIdx.x;
  const int b = wg >> 3;
  const int sub = wg & 7;
  const int tid = threadIdx.x;
  const int q = tid & 3;
  const int cl = tid >> 2;
  const int j = sub * 64 + cl;

  // ---- load + pack weights into registers ----
  uint32_t wr[64], wz[64], wn[64];
  {
    const float4* s0 = (const float4*)(Whh + (size_t)j * H_ + q * 128);
    const float4* s1 = (const float4*)(Whh + (size_t)(j + H_) * H_ + q * 128);
    const float4* s2 = (const float4*)(Whh + (size_t)(j + 2 * H_) * H_ + q * 128);
#pragma unroll
    for (int i = 0; i < 32; ++i) {
      float4 v0 = s0[i]; wr[2 * i] = packh2(v0.x, v0.y); wr[2 * i + 1] = packh2(v0.z, v0.w);
      float4 v1 = s1[i]; wz[2 * i] = packh2(v1.x, v1.y); wz[2 * i + 1] = packh2(v1.z, v1.w);
      float4 v2 = s2[i]; wn[2 * i] = packh2(v2.x, v2.y); wn[2 * i + 1] = packh2(v2.z, v2.w);
    }
  }
  const float bnj = bn[j];

  // padded LDS h (f16 halves): 4 quarters x (128 halves + 8 pad) = 272 u32 dwords? (stored as u32 pairs)
  __shared__ uint32_t hl[4 * 68];
  for (int i = tid; i < 4 * 68; i += 256) hl[i] = 0;
  __syncthreads();

  float hprev = 0.0f;

  for (int t = 0; t < T_; ++t) {
    // issue igate loads early (independent of h)
    const size_t igbase = ((size_t)b * T_ + t) * G3_;
    const float igr = (float)ig[igbase + j];
    const float igz = (float)ig[igbase + j + H_];
    const float ign = (float)ig[igbase + j + 2 * H_];

    if (t > 0) {
      // poll buf[t&1] for tag == t (512 words, 2 per thread)
      uint32_t* pb = hbuf + (size_t)(t & 1) * (B_ * H_) + (size_t)b * H_;
      const int k0 = 2 * tid;
      const uint32_t want = (uint32_t)t;
      uint32_t v0 = 0, v1 = 0;
      bool d0 = false, d1 = false;
      int guard = 0;
      for (;;) {
        if (!d0) {
          uint32_t v = __hip_atomic_load(&pb[k0], __ATOMIC_RELAXED, __HIP_MEMORY_SCOPE_AGENT);
          if ((v >> 16) == want) { v0 = v; d0 = true; }
        }
        if (!d1) {
          uint32_t v = __hip_atomic_load(&pb[k0 + 1], __ATOMIC_RELAXED, __HIP_MEMORY_SCOPE_AGENT);
          if ((v >> 16) == want) { v1 = v; d1 = true; }
        }
        if (++guard > 8192) {  // emergency: poison with +inf f16 so failure is visible, no hang
          if (!d0) v0 = 0x7C00u;
          if (!d1) v1 = 0x7C00u;
          d0 = d1 = true;
        }
        if (__syncthreads_and((int)(d0 && d1))) break;
      }
      // write my 2 halves into padded LDS: wave w owns quarter w
      hl[(tid >> 6) * 68 + (tid & 63)] = (v0 & 0xFFFFu) | (v1 << 16);
      __syncthreads();
    }

    // ---- dot: 3 gate rows, K-quarter q ----
    float ar = 0.0f, az = 0.0f, an = 0.0f;
    const uint4* hq = (const uint4*)(&hl[q * 68]);
#pragma unroll
    for (int i = 0; i < 16; ++i) {
      uint4 hv = hq[i];
      ar = fdot2f(wr[4 * i + 0], hv.x, ar); az = fdot2f(wz[4 * i + 0], hv.x, az); an = fdot2f(wn[4 * i + 0], hv.x, an);
      ar = fdot2f(wr[4 * i + 1], hv.y, ar); az = fdot2f(wz[4 * i + 1], hv.y, az); an = fdot2f(wn[4 * i + 1], hv.y, an);
      ar = fdot2f(wr[4 * i + 2], hv.z, ar); az = fdot2f(wz[4 * i + 2], hv.z, az); an = fdot2f(wn[4 * i + 2], hv.z, an);
      ar = fdot2f(wr[4 * i + 3], hv.w, ar); az = fdot2f(wz[4 * i + 3], hv.w, az); an = fdot2f(wn[4 * i + 3], hv.w, an);
    }
    // reduce across 4 K-quarter lanes (same wave, lanes 4c..4c+3)
    ar += __shfl_xor(ar, 1); ar += __shfl_xor(ar, 2);
    az += __shfl_xor(az, 1); az += __shfl_xor(az, 2);
    an += __shfl_xor(an, 1); an += __shfl_xor(an, 2);

    // ---- gates ----
    const float r = sigmoidf_(igr + ar);
    const float z = sigmoidf_(igz + az);
    const float n = tanhf_(ign + r * (an + bnj));
    const float hnew = n + z * (hprev - n);
    hprev = hnew;

    if (q == 0) {
      out[((size_t)b * T_ + t) * H_ + j] = hnew;
      uint32_t wv = ((uint32_t)(t + 1) << 16) | f16bits(hnew);
      __hip_atomic_store(&hbuf[(size_t)((t + 1) & 1) * (B_ * H_) + (size_t)b * H_ + j], wv,
                         __ATOMIC_RELAXED, __HIP_MEMORY_SCOPE_AGENT);
    }
  }
}

// ---------------- Fallback: naive (only if ws too small) ----------------
__global__ void __launch_bounds__(512) naive_kernel(const float* __restrict__ xs,
                                                    const float* __restrict__ Wih,
                                                    const float* __restrict__ Whh,
                                                    const float* __restrict__ bias,
                                                    const float* __restrict__ bn,
                                                    float* __restrict__ out) {
  const int b = blockIdx.x;
  const int j = threadIdx.x;
  __shared__ float h[H_];
  __shared__ float xr[D_];
  h[j] = 0.0f;
  __syncthreads();
  for (int t = 0; t < T_; ++t) {
    if (j < D_) xr[j] = xs[((size_t)b * T_ + t) * D_ + j];
    __syncthreads();
    float a[3];
#pragma unroll
    for (int g = 0; g < 3; ++g) {
      const int row = j + g * H_;
      float s = bias[row];
      const float* wi = Wih + (size_t)row * D_;
      for (int d = 0; d < D_; ++d) s = fmaf(wi[d], xr[d], s);
      const float* wh = Whh + (size_t)row * H_;
      for (int k = 0; k < H_; ++k) s = fmaf(wh[k], h[k], s);
      a[g] = s;
    }
    const float r = sigmoidf_(a[0]);
    const float z = sigmoidf_(a[1]);
    const float n = tanhf_(a[2] + (r - 1.0f) * 0.0f + r * 0.0f + (r * (0.0f)) + (a[2] * 0.0f));
    // recompute n correctly (a[2] currently includes W_hh@h; need r*(h_n + b_n) form):
    // a[2] = i_n + h_n  where i_n includes bias b; we need i_n + r*(h_n + b_n).
    (void)n;
    // redo with separated terms:
    float i_n = bias[j + 2 * H_];
    {
      const float* wi = Wih + (size_t)(j + 2 * H_) * D_;
      for (int d = 0; d < D_; ++d) i_n = fmaf(wi[d], xr[d], i_n);
    }
    float h_n = 0.0f;
    {
      const float* wh = Whh + (size_t)(j + 2 * H_) * H_;
      for (int k = 0; k < H_; ++k) h_n = fmaf(wh[k], h[k], h_n);
    }
    const float nn = tanhf_(i_n + r * (h_n + bn[j]));
    const float hnew = nn + z * (h[j] - nn);
    __syncthreads();
    h[j] = hnew;
    out[((size_t)b * T_ + t) * H_ + j] = hnew;
  }
}

extern "C" void kernel_launch(void* const* d_in, const int* in_sizes, int n_in,
                              void* d_out, int out_size, void* d_ws, size_t ws_size,
                              hipStream_t stream) {
  const float* xs  = (const float*)d_in[0];
  const float* Wih = (const float*)d_in[1];
  const float* Whh = (const float*)d_in[2];
  const float* bia = (const float*)d_in[3];
  const float* bnp = (const float*)d_in[4];
  float* out = (float*)d_out;

  if (ws_size >= WS_NEED) {
    char* ws = (char*)d_ws;
    _Float16* igp = (_Float16*)(ws + OFF_IG);
    float* wtp = (float*)(ws + OFF_WT);
    uint32_t* hbuf = (uint32_t*)(ws + OFF_HBUF);

    // zero tag buffer (kills stale tags from prior replays; required for correctness)
    hipMemsetAsync(hbuf, 0, 2 * B_ * H_ * sizeof(uint32_t), stream);

    wt_kernel<<<dim3(384), dim3(256), 0, stream>>>(Wih, (float4*)wtp);
    ig_kernel<<<dim3((B_ * T_) / 16), dim3(256), 0, stream>>>(xs, wtp, bia, igp);
    rec_kernel<<<dim3(128), dim3(256), 0, stream>>>(igp, Whh, bnp, hbuf, out);
  } else {
    naive_kernel<<<dim3(B_), dim3(H_), 0, stream>>>(xs, Wih, Whh, bia, bnp, out);
  }
}

// Round 2
// 8927.428 us; speedup vs baseline: 1.1150x; 1.1150x over previous
//
#include <hip/hip_runtime.h>
#include <stdint.h>
#include <stddef.h>

#define B_ 16
#define T_ 4096
#define D_ 256
#define H_ 512
#define G3_ 1536

// ws layout
#define OFF_IG   ((size_t)0)                       // igates f16: 65536*1536*2 = 201326592
#define OFF_WT   ((size_t)201326592)               // W_ih^T packed float4: 256*1536*4 = 1572864
#define OFF_MB   ((size_t)202899456)               // mailboxes: 2*16*8*512*4 = 262144
#define WS_NEED  ((size_t)203161600)

typedef _Float16 h2_t __attribute__((ext_vector_type(2)));

#if defined(__has_builtin)
#if __has_builtin(__builtin_amdgcn_fdot2)
#define HAVE_FDOT2 1
#endif
#endif

__device__ __forceinline__ float fdot2f(uint32_t w, uint32_t h, float acc) {
  union { uint32_t u; h2_t v; } a, b;
  a.u = w; b.u = h;
#ifdef HAVE_FDOT2
  return __builtin_amdgcn_fdot2(a.v, b.v, acc, false);
#else
  return fmaf((float)a.v.x, (float)b.v.x, fmaf((float)a.v.y, (float)b.v.y, acc));
#endif
}

__device__ __forceinline__ uint32_t packh2(float a, float b) {
  union { h2_t v; uint32_t u; } x;
  x.v.x = (_Float16)a; x.v.y = (_Float16)b;
  return x.u;
}

__device__ __forceinline__ uint32_t f16bits(float a) {
  union { _Float16 h; uint16_t u; } x;
  x.h = (_Float16)a;
  return (uint32_t)x.u;
}

__device__ __forceinline__ float h2f(uint16_t u) {
  union { _Float16 h; uint16_t u; } x;
  x.u = u;
  return (float)x.h;
}

__device__ __forceinline__ float sigmoidf_(float x) {
  return 1.0f / (1.0f + __expf(-x));
}

__device__ __forceinline__ float tanhf_(float x) {
  x = fminf(fmaxf(x, -15.0f), 15.0f);
  float e = __expf(-2.0f * x);
  return (1.0f - e) / (1.0f + e);
}

// ---------------- Kernel 1: transpose+pack W_ih into [d/4][g] float4 ----------------
__global__ void __launch_bounds__(256) wt_kernel(const float* __restrict__ W, float4* __restrict__ Wt4) {
  int idx = blockIdx.x * 256 + threadIdx.x;   // over 1536*64
  if (idx >= G3_ * 64) return;
  int g = idx % G3_;
  int d4 = idx / G3_;
  float4 v = *(const float4*)(W + (size_t)g * D_ + 4 * d4);
  Wt4[(size_t)d4 * G3_ + g] = v;
}

// ---------------- Kernel 2: igates = xs @ W_ih^T + b  -> f16 ----------------
__global__ void __launch_bounds__(256) ig_kernel(const float* __restrict__ xs,
                                                 const float* __restrict__ Wt,
                                                 const float* __restrict__ bias,
                                                 _Float16* __restrict__ ig) {
  __shared__ float xls[16 * 256];
  const int m0 = blockIdx.x * 16;
  const int tid = threadIdx.x;

  const float4* xsrc = (const float4*)(xs + (size_t)m0 * D_);
  float4* xdst = (float4*)xls;
#pragma unroll
  for (int k = 0; k < 4; ++k) xdst[tid + 256 * k] = xsrc[tid + 256 * k];
  __syncthreads();

  float acc[6][16];
#pragma unroll
  for (int k = 0; k < 6; ++k)
#pragma unroll
    for (int m = 0; m < 16; ++m) acc[k][m] = 0.0f;

  const float4* Wt4 = (const float4*)Wt;
  const float4* lds4 = (const float4*)xls;

  for (int d4 = 0; d4 < 64; ++d4) {
    float4 w[6];
#pragma unroll
    for (int k = 0; k < 6; ++k) w[k] = Wt4[(size_t)d4 * G3_ + tid + 256 * k];
#pragma unroll
    for (int m = 0; m < 16; ++m) {
      float4 xv = lds4[m * 64 + d4];
#pragma unroll
      for (int k = 0; k < 6; ++k) {
        acc[k][m] = fmaf(w[k].x, xv.x, acc[k][m]);
        acc[k][m] = fmaf(w[k].y, xv.y, acc[k][m]);
        acc[k][m] = fmaf(w[k].z, xv.z, acc[k][m]);
        acc[k][m] = fmaf(w[k].w, xv.w, acc[k][m]);
      }
    }
  }

#pragma unroll
  for (int k = 0; k < 6; ++k) {
    float bb = bias[tid + 256 * k];
#pragma unroll
    for (int m = 0; m < 16; ++m) {
      ig[(size_t)(m0 + m) * G3_ + tid + 256 * k] = (_Float16)(acc[k][m] + bb);
    }
  }
}

// ---------------- Kernel 3: persistent recurrence ----------------
// 128 WGs x 256 threads. WG wg: batch b = wg>>3, col slice sub = wg&7 (64 h-cols).
// Thread: q = tid&3 (K-quarter), cl = tid>>2 (local col), j = sub*64+cl.
// Exchange via PRIVATE per-consumer mailboxes of tagged words (tag<<16)|f16(h),
// double-buffered; producer thread q replicates its value to consumers {q, q+4}.
// Barrier-free per-thread spin; two block barriers per step (stage / read-complete).
__global__ void __launch_bounds__(256, 1) rec_kernel(const _Float16* __restrict__ ig,
                                                     const float* __restrict__ Whh,
                                                     const float* __restrict__ bn,
                                                     uint32_t* __restrict__ mb,
                                                     float* __restrict__ out) {
  const int wg = blockIdx.x;
  const int b = wg >> 3;
  const int sub = wg & 7;
  const int tid = threadIdx.x;
  const int q = tid & 3;
  const int cl = tid >> 2;
  const int j = sub * 64 + cl;

  // ---- load + pack weights into registers ----
  uint32_t wr[64], wz[64], wn[64];
  {
    const float4* s0 = (const float4*)(Whh + (size_t)j * H_ + q * 128);
    const float4* s1 = (const float4*)(Whh + (size_t)(j + H_) * H_ + q * 128);
    const float4* s2 = (const float4*)(Whh + (size_t)(j + 2 * H_) * H_ + q * 128);
#pragma unroll
    for (int i = 0; i < 32; ++i) {
      float4 v0 = s0[i]; wr[2 * i] = packh2(v0.x, v0.y); wr[2 * i + 1] = packh2(v0.z, v0.w);
      float4 v1 = s1[i]; wz[2 * i] = packh2(v1.x, v1.y); wz[2 * i + 1] = packh2(v1.z, v1.w);
      float4 v2 = s2[i]; wn[2 * i] = packh2(v2.x, v2.y); wn[2 * i + 1] = packh2(v2.z, v2.w);
    }
  }
  const float bnj = bn[j];

  // padded LDS h: 4 quarters x (64 u32 + 4 pad)
  __shared__ uint32_t hl[4 * 68];
  for (int i = tid; i < 4 * 68; i += 256) hl[i] = 0;
  __syncthreads();

  float hprev = 0.0f;

  // my consumer mailbox base (batch b, consumer sub); parity-major
  const size_t mb_bc = ((size_t)b * 8 + sub) * 512;
  const size_t par_stride = (size_t)B_ * 8 * 512;
  // producer destinations: consumers q and q+4 of batch b, word j
  const size_t dst0 = ((size_t)b * 8 + q) * 512 + (size_t)j;
  const size_t dst1 = ((size_t)b * 8 + (q + 4)) * 512 + (size_t)j;

  const uint16_t* ig16 = (const uint16_t*)ig;
  size_t igbase = (size_t)b * T_ * G3_;

  // preload ig[t=0] raw
  uint16_t cr = ig16[igbase + j];
  uint16_t cz = ig16[igbase + j + H_];
  uint16_t cn = ig16[igbase + j + 2 * H_];

  for (int t = 0; t < T_; ++t) {
    // prefetch next-step ig raw (HBM latency hides under the poll)
    uint16_t nr = 0, nz = 0, nn_ = 0;
    if (t + 1 < T_) {
      const size_t nb = igbase + G3_;
      nr = ig16[nb + j];
      nz = ig16[nb + j + H_];
      nn_ = ig16[nb + j + 2 * H_];
    }

    if (t > 0) {
      // barrier-free spin on my 2 private words
      const uint32_t* pb = mb + (size_t)(t & 1) * par_stride + mb_bc;
      const int k0 = 2 * tid;
      const uint32_t want = (uint32_t)t;
      uint32_t v0 = 0, v1 = 0;
      bool d0 = false, d1 = false;
      int guard = 0;
      for (;;) {
        uint32_t a0 = 0, a1 = 0;
        if (!d0) a0 = __hip_atomic_load(&pb[k0], __ATOMIC_RELAXED, __HIP_MEMORY_SCOPE_AGENT);
        if (!d1) a1 = __hip_atomic_load(&pb[k0 + 1], __ATOMIC_RELAXED, __HIP_MEMORY_SCOPE_AGENT);
        if (!d0 && (a0 >> 16) == want) { v0 = a0; d0 = true; }
        if (!d1 && (a1 >> 16) == want) { v1 = a1; d1 = true; }
        if (d0 && d1) break;
        if (++guard > 65536) {  // emergency: poison so failure is visible, no hang
          if (!d0) v0 = 0x7C00u;
          if (!d1) v1 = 0x7C00u;
          break;
        }
      }
      // stage into LDS: word k0 = col 2*tid -> quarter tid>>6, u32 slot tid&63
      hl[(tid >> 6) * 68 + (tid & 63)] = (v0 & 0xFFFFu) | (v1 << 16);
      __syncthreads();  // barrier1: all stages visible
    }

    // ---- dot: 3 gate rows, K-quarter q; split chains to cut dep latency ----
    float ar0 = 0.0f, az0 = 0.0f, an0 = 0.0f;
    float ar1 = 0.0f, az1 = 0.0f, an1 = 0.0f;
    const uint4* hq = (const uint4*)(&hl[q * 68]);
#pragma unroll
    for (int i = 0; i < 8; ++i) {
      uint4 hv = hq[i];
      ar0 = fdot2f(wr[4 * i + 0], hv.x, ar0); az0 = fdot2f(wz[4 * i + 0], hv.x, az0); an0 = fdot2f(wn[4 * i + 0], hv.x, an0);
      ar0 = fdot2f(wr[4 * i + 1], hv.y, ar0); az0 = fdot2f(wz[4 * i + 1], hv.y, az0); an0 = fdot2f(wn[4 * i + 1], hv.y, an0);
      ar0 = fdot2f(wr[4 * i + 2], hv.z, ar0); az0 = fdot2f(wz[4 * i + 2], hv.z, az0); an0 = fdot2f(wn[4 * i + 2], hv.z, an0);
      ar0 = fdot2f(wr[4 * i + 3], hv.w, ar0); az0 = fdot2f(wz[4 * i + 3], hv.w, az0); an0 = fdot2f(wn[4 * i + 3], hv.w, an0);
    }
#pragma unroll
    for (int i = 8; i < 16; ++i) {
      uint4 hv = hq[i];
      ar1 = fdot2f(wr[4 * i + 0], hv.x, ar1); az1 = fdot2f(wz[4 * i + 0], hv.x, az1); an1 = fdot2f(wn[4 * i + 0], hv.x, an1);
      ar1 = fdot2f(wr[4 * i + 1], hv.y, ar1); az1 = fdot2f(wz[4 * i + 1], hv.y, az1); an1 = fdot2f(wn[4 * i + 1], hv.y, an1);
      ar1 = fdot2f(wr[4 * i + 2], hv.z, ar1); az1 = fdot2f(wz[4 * i + 2], hv.z, az1); an1 = fdot2f(wn[4 * i + 2], hv.z, an1);
      ar1 = fdot2f(wr[4 * i + 3], hv.w, ar1); az1 = fdot2f(wz[4 * i + 3], hv.w, an1 == an1 ? az1 : az1); an1 = fdot2f(wn[4 * i + 3], hv.w, an1);
    }
    __syncthreads();  // barrier2: all LDS reads done before anyone stages t+1

    float ar = ar0 + ar1, az = az0 + az1, an = an0 + an1;
    // reduce across 4 K-quarter lanes (same wave, lanes 4c..4c+3)
    ar += __shfl_xor(ar, 1); ar += __shfl_xor(ar, 2);
    az += __shfl_xor(az, 1); az += __shfl_xor(az, 2);
    an += __shfl_xor(an, 1); an += __shfl_xor(an, 2);

    // ---- gates ----
    const float igr = h2f(cr), igz = h2f(cz), ign = h2f(cn);
    const float r = sigmoidf_(igr + ar);
    const float z = sigmoidf_(igz + az);
    const float n = tanhf_(ign + r * (an + bnj));
    const float hnew = n + z * (hprev - n);
    hprev = hnew;

    // ---- publish: 2 private-mailbox copies per thread (all 4 q-lanes have identical hnew) ----
    const uint32_t wv = ((uint32_t)(t + 1) << 16) | f16bits(hnew);
    uint32_t* nbuf = mb + (size_t)((t + 1) & 1) * par_stride;
    __hip_atomic_store(&nbuf[dst0], wv, __ATOMIC_RELAXED, __HIP_MEMORY_SCOPE_AGENT);
    __hip_atomic_store(&nbuf[dst1], wv, __ATOMIC_RELAXED, __HIP_MEMORY_SCOPE_AGENT);

    if (q == 0) {
      out[((size_t)b * T_ + t) * H_ + j] = hnew;
    }

    // rotate ig prefetch
    cr = nr; cz = nz; cn = nn_;
    igbase += G3_;
  }
}

// ---------------- Fallback: naive (only if ws too small) ----------------
__global__ void __launch_bounds__(512) naive_kernel(const float* __restrict__ xs,
                                                    const float* __restrict__ Wih,
                                                    const float* __restrict__ Whh,
                                                    const float* __restrict__ bias,
                                                    const float* __restrict__ bn,
                                                    float* __restrict__ out) {
  const int b = blockIdx.x;
  const int j = threadIdx.x;
  __shared__ float h[H_];
  __shared__ float xr[D_];
  h[j] = 0.0f;
  __syncthreads();
  for (int t = 0; t < T_; ++t) {
    if (j < D_) xr[j] = xs[((size_t)b * T_ + t) * D_ + j];
    __syncthreads();
    float a[2];
#pragma unroll
    for (int g = 0; g < 2; ++g) {
      const int row = j + g * H_;
      float s = bias[row];
      const float* wi = Wih + (size_t)row * D_;
      for (int d = 0; d < D_; ++d) s = fmaf(wi[d], xr[d], s);
      const float* wh = Whh + (size_t)row * H_;
      for (int k = 0; k < H_; ++k) s = fmaf(wh[k], h[k], s);
      a[g] = s;
    }
    const float r = sigmoidf_(a[0]);
    const float z = sigmoidf_(a[1]);
    float i_n = bias[j + 2 * H_];
    {
      const float* wi = Wih + (size_t)(j + 2 * H_) * D_;
      for (int d = 0; d < D_; ++d) i_n = fmaf(wi[d], xr[d], i_n);
    }
    float h_n = 0.0f;
    {
      const float* wh = Whh + (size_t)(j + 2 * H_) * H_;
      for (int k = 0; k < H_; ++k) h_n = fmaf(wh[k], h[k], h_n);
    }
    const float nn = tanhf_(i_n + r * (h_n + bn[j]));
    const float hnew = nn + z * (h[j] - nn);
    __syncthreads();
    h[j] = hnew;
    out[((size_t)b * T_ + t) * H_ + j] = hnew;
  }
}

extern "C" void kernel_launch(void* const* d_in, const int* in_sizes, int n_in,
                              void* d_out, int out_size, void* d_ws, size_t ws_size,
                              hipStream_t stream) {
  const float* xs  = (const float*)d_in[0];
  const float* Wih = (const float*)d_in[1];
  const float* Whh = (const float*)d_in[2];
  const float* bia = (const float*)d_in[3];
  const float* bnp = (const float*)d_in[4];
  float* out = (float*)d_out;

  if (ws_size >= WS_NEED) {
    char* ws = (char*)d_ws;
    _Float16* igp = (_Float16*)(ws + OFF_IG);
    float* wtp = (float*)(ws + OFF_WT);
    uint32_t* mbp = (uint32_t*)(ws + OFF_MB);

    // zero tag mailboxes (kills stale tags from prior replays; required for correctness)
    hipMemsetAsync(mbp, 0, 2 * B_ * 8 * 512 * sizeof(uint32_t), stream);

    wt_kernel<<<dim3(384), dim3(256), 0, stream>>>(Wih, (float4*)wtp);
    ig_kernel<<<dim3((B_ * T_) / 16), dim3(256), 0, stream>>>(xs, wtp, bia, igp);
    rec_kernel<<<dim3(128), dim3(256), 0, stream>>>(igp, Whh, bnp, mbp, out);
  } else {
    naive_kernel<<<dim3(B_), dim3(H_), 0, stream>>>(xs, Wih, Whh, bia, bnp, out);
  }
}